// Round 4
// baseline (177.432 us; speedup 1.0000x reference)
//
#include <hip/hip_runtime.h>

#define NPTS 200000
#define MWORDS 25000
#define NCHUNK 98          // ceil(25000/256) chunks of 256 words
#define NSLOT 64

// ---------- workspace layout (bytes) ----------
#define WS_PREFIX    0          // 8*25000*4 = 800000
#define WS_BLOCKSUM  800000     // 8*98*4    = 3136
#define WS_SLOTS     803136     // 64*72*4   = 18432
#define WS_CAM       821568     // 8*20*4    = 640

// ---------- DPP wave-64 reductions (sum lands in lane 63) ----------
__device__ __forceinline__ float wred_f(float x) {
    x += __int_as_float(__builtin_amdgcn_update_dpp(0, __float_as_int(x), 0x111, 0xf, 0xf, true)); // row_shr:1
    x += __int_as_float(__builtin_amdgcn_update_dpp(0, __float_as_int(x), 0x112, 0xf, 0xf, true)); // row_shr:2
    x += __int_as_float(__builtin_amdgcn_update_dpp(0, __float_as_int(x), 0x114, 0xf, 0xf, true)); // row_shr:4
    x += __int_as_float(__builtin_amdgcn_update_dpp(0, __float_as_int(x), 0x118, 0xf, 0xf, true)); // row_shr:8
    x += __int_as_float(__builtin_amdgcn_update_dpp(0, __float_as_int(x), 0x142, 0xf, 0xf, true)); // row_bcast:15
    x += __int_as_float(__builtin_amdgcn_update_dpp(0, __float_as_int(x), 0x143, 0xf, 0xf, true)); // row_bcast:31
    return x;
}
__device__ __forceinline__ int wred_i(int x) {
    x += __builtin_amdgcn_update_dpp(0, x, 0x111, 0xf, 0xf, true);
    x += __builtin_amdgcn_update_dpp(0, x, 0x112, 0xf, 0xf, true);
    x += __builtin_amdgcn_update_dpp(0, x, 0x114, 0xf, 0xf, true);
    x += __builtin_amdgcn_update_dpp(0, x, 0x118, 0xf, 0xf, true);
    x += __builtin_amdgcn_update_dpp(0, x, 0x142, 0xf, 0xf, true);
    x += __builtin_amdgcn_update_dpp(0, x, 0x143, 0xf, 0xf, true);
    return x;
}

// ---------- kernel P1: per-chunk local scan + blocksum + misc init ----------
__global__ __launch_bounds__(256) void scan1_kernel(const int* __restrict__ mask,
                                                    int* __restrict__ prefix,
                                                    int* __restrict__ blocksum,
                                                    float* __restrict__ slots,
                                                    float* __restrict__ cam,
                                                    const float* __restrict__ viewmats,
                                                    const float* __restrict__ Ks,
                                                    const int* __restrict__ pw,
                                                    const int* __restrict__ ph) {
    const int tid = threadIdx.x;
    if (blockIdx.x == NCHUNK) {               // misc block
        if (blockIdx.y != 0) return;
        for (int i = tid; i < NSLOT * 72; i += 256) slots[i] = 0.f;
        if (tid < 8) {
            const int bc = tid;
            float* cp = cam + bc * 20;
            const int vbase = bc * 16;
            for (int i = 0; i < 3; i++) {
                for (int j = 0; j < 3; j++) cp[i*3 + j] = viewmats[vbase + i*4 + j];
                cp[9 + i] = viewmats[vbase + i*4 + 3];
            }
            const int kbase = bc * 9;
            float fx = Ks[kbase + 0], fy = Ks[kbase + 4];
            float cx = Ks[kbase + 2], cy = Ks[kbase + 5];
            int wi = *pw, hi = *ph;
            float W = (wi >= 1 && wi <= (1 << 20)) ? (float)wi : __int_as_float(wi);
            float H = (hi >= 1 && hi <= (1 << 20)) ? (float)hi : __int_as_float(hi);
            float tanx = 0.5f * W / fx, tany = 0.5f * H / fy;
            cp[12] = fx; cp[13] = fy;
            cp[14] = (W - cx) / fx + 0.3f * tanx;
            cp[15] = cx / fx + 0.3f * tanx;
            cp[16] = (H - cy) / fy + 0.3f * tany;
            cp[17] = cy / fy + 0.3f * tany;
        }
        return;
    }
    const int bc    = blockIdx.y;
    const int chunk = blockIdx.x;
    const int lane  = tid & 63, wv = tid >> 6;
    const int w = chunk * 256 + tid;
    const int base = bc * MWORDS;

    int p = (w < MWORDS) ? __popc(mask[base + w]) : 0;
    int v = p;
#pragma unroll
    for (int off = 1; off < 64; off <<= 1) {
        int u = __shfl_up(v, off, 64);
        if (lane >= off) v += u;
    }
    __shared__ int wsum[4];
    if (lane == 63) wsum[wv] = v;
    __syncthreads();
    int wadd = 0;
#pragma unroll
    for (int i = 0; i < 4; i++) if (i < wv) wadd += wsum[i];
    if (w < MWORDS) prefix[base + w] = v - p + wadd;
    if (tid == 255) blocksum[bc * NCHUNK + chunk] = wadd + v;
}

// ---------- kernel 2: main backward ----------
__global__ __launch_bounds__(256) void main_kernel(
    const float* __restrict__ means,
    const float* __restrict__ quats,
    const float* __restrict__ scales,
    const float* __restrict__ conics,
    const float* __restrict__ v_m2d,
    const float* __restrict__ v_dep,
    const float* __restrict__ v_con,
    const float* __restrict__ v_col,
    const float* __restrict__ v_op,
    const int* __restrict__ mask,
    const int* __restrict__ prefix,
    const int* __restrict__ blocksum,
    const float* __restrict__ cam,
    float* __restrict__ slots,
    float* __restrict__ out)
{
    const int O_PW = 0, O_QU = 1200000, O_SC = 2800000, O_CL = 4000072, O_OP = 5200072;
    const int b = blockIdx.y;
    const int n = blockIdx.x * 256 + threadIdx.x;
    const bool act = (n < NPTS);
    const int nc = act ? n : (NPTS - 1);          // clamped index for loads
    const int lane = threadIdx.x & 63, wv = threadIdx.x >> 6;
    const int slot = blockIdx.x & (NSLOT - 1);

    // ---- per-block chunk prefix (one camera per wave), DPP reduce ----
    const int chk = blockIdx.x >> 3;              // 256-word chunk id
    __shared__ int cpf_lds[4];
    {
        const int bcw = b * 4 + wv;
        int s0 = (lane < chk) ? blocksum[bcw * NCHUNK + lane] : 0;
        if (lane + 64 < chk) s0 += blocksum[bcw * NCHUNK + lane + 64];
        int tot = wred_i(s0);
        int t = __builtin_amdgcn_readlane(tot, 63);
        if (lane == 0) cpf_lds[wv] = t;
    }

    // hoisted mask/prefix loads for all 4 cameras
    const int w_ = nc >> 3, bit = nc & 7;
    int words[4], pref[4];
#pragma unroll
    for (int c = 0; c < 4; c++) {
        const int bc = b*4 + c;
        words[c] = mask[bc*MWORDS + w_];
        pref[c]  = prefix[bc*MWORDS + w_];
    }

    float mn0 = means[(b*3+0)*NPTS + nc];
    float mn1 = means[(b*3+1)*NPTS + nc];
    float mn2 = means[(b*3+2)*NPTS + nc];
    float q0 = quats[(b*4+0)*NPTS + nc];
    float q1 = quats[(b*4+1)*NPTS + nc];
    float q2 = quats[(b*4+2)*NPTS + nc];
    float q3 = quats[(b*4+3)*NPTS + nc];
    float sc0 = scales[(b*3+0)*NPTS + nc];
    float sc1 = scales[(b*3+1)*NPTS + nc];
    float sc2 = scales[(b*3+2)*NPTS + nc];
    float inv_norm = rsqrtf(q0*q0 + q1*q1 + q2*q2 + q3*q3);
    float qw = q0*inv_norm, qx = q1*inv_norm, qy = q2*inv_norm, qz = q3*inv_norm;
    float R00 = 1.f - 2.f*(qy*qy + qz*qz), R01 = 2.f*(qx*qy - qw*qz), R02 = 2.f*(qx*qz + qw*qy);
    float R10 = 2.f*(qx*qy + qw*qz), R11 = 1.f - 2.f*(qx*qx + qz*qz), R12 = 2.f*(qy*qz - qw*qx);
    float R20 = 2.f*(qx*qz - qw*qy), R21 = 2.f*(qy*qz + qw*qx), R22 = 1.f - 2.f*(qx*qx + qy*qy);
    float M00 = R00*sc0, M01 = R01*sc1, M02 = R02*sc2;
    float M10 = R10*sc0, M11 = R11*sc1, M12 = R12*sc2;
    float M20 = R20*sc0, M21 = R21*sc1, M22 = R22*sc2;
    float cv00 = M00*M00 + M01*M01 + M02*M02;
    float cv01 = M00*M10 + M01*M11 + M02*M12;
    float cv02 = M00*M20 + M01*M21 + M02*M22;
    float cv11 = M10*M10 + M11*M11 + M12*M12;
    float cv12 = M10*M20 + M11*M21 + M12*M22;
    float cv22 = M20*M20 + M21*M21 + M22*M22;

    float H00=0,H01=0,H02=0,H11=0,H12=0,H22=0;
    float vpw0=0,vpw1=0,vpw2=0;
    float vcl0=0,vcl1=0,vcl2=0, vopo=0;

    __syncthreads();   // cpf_lds ready

#pragma unroll
    for (int c = 0; c < 4; c++) {
        const int bc = b*4 + c;
        const float* cp = cam + bc*20;
        const bool go = act && ((words[c] >> bit) & 1);
        float rv0=0,rv1=0,rv2=0,rv3=0,rv4=0,rv5=0,rv6=0,rv7=0,rv8=0;
        if (go) {
            const float V00=cp[0],V01=cp[1],V02=cp[2],V10=cp[3],V11=cp[4],V12=cp[5],V20=cp[6],V21=cp[7],V22=cp[8];
            const float t0=cp[9], t1=cp[10], t2=cp[11];
            const float fx=cp[12], fy=cp[13], lxp=cp[14], lxn=cp[15], lyp=cp[16], lyn=cp[17];
            const int r = pref[c] + cpf_lds[c] + __popc(words[c] & ((1 << bit) - 1));
            const int base3 = bc*3*NPTS, base2 = bc*2*NPTS, base1 = bc*NPTS;
            float g_c0 = v_con[base3 + r];
            float g_c1 = v_con[base3 + NPTS + r];
            float g_c2 = v_con[base3 + 2*NPTS + r];
            float g_m0 = v_m2d[base2 + r];
            float g_m1 = v_m2d[base2 + NPTS + r];
            float g_d  = v_dep[base1 + r];
            float g_l0 = v_col[base3 + r];
            float g_l1 = v_col[base3 + NPTS + r];
            float g_l2 = v_col[base3 + 2*NPTS + r];
            float g_o  = v_op[base1 + r];
            float p00 = conics[base3 + nc];
            float p01 = conics[base3 + NPTS + nc];
            float p11 = conics[base3 + 2*NPTS + nc];
            // U = -P (v_ci) P   (symmetric)
            float a00 = g_c0, a01 = 0.5f*g_c1, a11 = g_c2;
            float q00 = a00*p00 + a01*p01, q01 = a00*p01 + a01*p11;
            float q10 = a01*p00 + a11*p01, q11 = a01*p01 + a11*p11;
            float u00 = -(p00*q00 + p01*q10), u01 = -(p00*q01 + p01*q11);
            float u10 = -(p01*q00 + p11*q10), u11 = -(p01*q01 + p11*q11);
            // mean_c
            float mx = V00*mn0 + V01*mn1 + V02*mn2 + t0;
            float my = V10*mn0 + V11*mn1 + V12*mn2 + t1;
            float tz = V20*mn0 + V21*mn1 + V22*mn2 + t2;
            float rz = 1.0f / tz;
            float rz2 = rz*rz, rz3 = rz2*rz;
            // T = Rv @ covars ; covar_c = T @ Rv^T (sym)
            float T00 = V00*cv00 + V01*cv01 + V02*cv02;
            float T01 = V00*cv01 + V01*cv11 + V02*cv12;
            float T02 = V00*cv02 + V01*cv12 + V02*cv22;
            float T10 = V10*cv00 + V11*cv01 + V12*cv02;
            float T11 = V10*cv01 + V11*cv11 + V12*cv12;
            float T12 = V10*cv02 + V11*cv12 + V12*cv22;
            float T20 = V20*cv00 + V21*cv01 + V22*cv02;
            float T21 = V20*cv01 + V21*cv11 + V22*cv12;
            float T22 = V20*cv02 + V21*cv12 + V22*cv22;
            float cc00 = T00*V00 + T01*V01 + T02*V02;
            float cc01 = T00*V10 + T01*V11 + T02*V12;
            float cc02 = T00*V20 + T01*V21 + T02*V22;
            float cc11 = T10*V10 + T11*V11 + T12*V12;
            float cc12 = T10*V20 + T11*V21 + T12*V22;
            float cc22 = T20*V20 + T21*V21 + T22*V22;
            // J terms
            float mxz = mx*rz, myz = my*rz;
            float xf = (mxz <= lxp && mxz >= -lxn) ? 1.f : 0.f;
            float yf = (myz <= lyp && myz >= -lyn) ? 1.f : 0.f;
            float tx = tz * fminf(fmaxf(mxz, -lxn), lxp);
            float ty = tz * fminf(fmaxf(myz, -lyn), lyp);
            float j00 = fx*rz, j02 = -fx*tx*rz2;
            float j11 = fy*rz, j12 = -fy*ty*rz2;
            // D = J^T U J ; S = D + D^T
            float W0a = u00*j00, W0b = u01*j11, W0c = u00*j02 + u01*j12;
            float W1a = u10*j00, W1b = u11*j11, W1c = u10*j02 + u11*j12;
            float d00 = j00*W0a, d01 = j00*W0b, d02 = j00*W0c;
            float d10 = j11*W1a, d11 = j11*W1b, d12 = j11*W1c;
            float d20 = j02*W0a + j12*W1a, d21 = j02*W0b + j12*W1b, d22 = j02*W0c + j12*W1c;
            float s00 = d00+d00, s01 = d01+d10, s02 = d02+d20;
            float s11 = d11+d11, s12 = d12+d21, s22 = d22+d22;
            // v_J = (2U) J covar_c
            float e00 = u00+u00, e01 = u01+u10, e11 = u11+u11;
            float X00 = e00*j00, X01 = e01*j11, X02 = e00*j02 + e01*j12;
            float X10 = e01*j00, X11 = e11*j11, X12 = e01*j02 + e11*j12;
            float vJ00 = X00*cc00 + X01*cc01 + X02*cc02;
            float vJ02 = X00*cc02 + X01*cc12 + X02*cc22;
            float vJ11 = X10*cc01 + X11*cc11 + X12*cc12;
            float vJ12 = X10*cc02 + X11*cc12 + X12*cc22;
            // v_mean_c
            float m0 = fx*rz*g_m0;
            float m1 = fy*rz*g_m1;
            float m2 = -(fx*mx*g_m0 + fy*my*g_m1)*rz2;
            m0 -= fx*rz2*vJ02*xf;
            m2 -= fx*rz3*vJ02*tx*(1.f - xf);
            m1 -= fy*rz2*vJ12*yf;
            m2 -= fy*rz3*vJ12*ty*(1.f - yf);
            m2 += -fx*rz2*vJ00 - fy*rz2*vJ11 + 2.f*fx*tx*rz3*vJ02 + 2.f*fy*ty*rz3*vJ12;
            m2 += g_d;
            // v_pW += Rv^T v_mean_c
            vpw0 += V00*m0 + V10*m1 + V20*m2;
            vpw1 += V01*m0 + V11*m1 + V21*m2;
            vpw2 += V02*m0 + V12*m1 + V22*m2;
            // v_Rview contribution = m ⊗ mean + S @ T
            rv0 = m0*mn0 + (s00*T00 + s01*T10 + s02*T20);
            rv1 = m0*mn1 + (s00*T01 + s01*T11 + s02*T21);
            rv2 = m0*mn2 + (s00*T02 + s01*T12 + s02*T22);
            rv3 = m1*mn0 + (s01*T00 + s11*T10 + s12*T20);
            rv4 = m1*mn1 + (s01*T01 + s11*T11 + s12*T21);
            rv5 = m1*mn2 + (s01*T02 + s11*T12 + s12*T22);
            rv6 = m2*mn0 + (s02*T00 + s12*T10 + s22*T20);
            rv7 = m2*mn1 + (s02*T01 + s12*T11 + s22*T21);
            rv8 = m2*mn2 + (s02*T02 + s12*T12 + s22*T22);
            // H += Rv^T S Rv
            float P00 = s00*V00 + s01*V10 + s02*V20;
            float P01 = s00*V01 + s01*V11 + s02*V21;
            float P02 = s00*V02 + s01*V12 + s02*V22;
            float P10 = s01*V00 + s11*V10 + s12*V20;
            float P11 = s01*V01 + s11*V11 + s12*V21;
            float P12 = s01*V02 + s11*V12 + s12*V22;
            float P20 = s02*V00 + s12*V10 + s22*V20;
            float P21 = s02*V01 + s12*V11 + s22*V21;
            float P22 = s02*V02 + s12*V12 + s22*V22;
            H00 += V00*P00 + V10*P10 + V20*P20;
            H01 += V00*P01 + V10*P11 + V20*P21;
            H02 += V00*P02 + V10*P12 + V20*P22;
            H11 += V01*P01 + V11*P11 + V21*P21;
            H12 += V01*P02 + V11*P12 + V21*P22;
            H22 += V02*P02 + V12*P12 + V22*P22;
            vcl0 += g_l0; vcl1 += g_l1; vcl2 += g_l2; vopo += g_o;
        }
        // ---- per-camera DPP wave reduce of rv (all lanes participate) ----
        rv0 = wred_f(rv0); rv1 = wred_f(rv1); rv2 = wred_f(rv2);
        rv3 = wred_f(rv3); rv4 = wred_f(rv4); rv5 = wred_f(rv5);
        rv6 = wred_f(rv6); rv7 = wred_f(rv7); rv8 = wred_f(rv8);
        if (lane == 63) {
            float* sp = slots + slot*72 + b*36 + c*9;
            atomicAdd(sp+0, rv0); atomicAdd(sp+1, rv1); atomicAdd(sp+2, rv2);
            atomicAdd(sp+3, rv3); atomicAdd(sp+4, rv4); atomicAdd(sp+5, rv5);
            atomicAdd(sp+6, rv6); atomicAdd(sp+7, rv7); atomicAdd(sp+8, rv8);
        }
    }

    if (act) {
        // v_M = H @ Mm
        float vM00 = H00*M00 + H01*M10 + H02*M20;
        float vM01 = H00*M01 + H01*M11 + H02*M21;
        float vM02 = H00*M02 + H01*M12 + H02*M22;
        float vM10 = H01*M00 + H11*M10 + H12*M20;
        float vM11 = H01*M01 + H11*M11 + H12*M21;
        float vM12 = H01*M02 + H11*M12 + H12*M22;
        float vM20 = H02*M00 + H12*M10 + H22*M20;
        float vM21 = H02*M01 + H12*M11 + H22*M21;
        float vM22 = H02*M02 + H12*M12 + H22*M22;
        float vs0 = R00*vM00 + R10*vM10 + R20*vM20;
        float vs1 = R01*vM01 + R11*vM11 + R21*vM21;
        float vs2 = R02*vM02 + R12*vM12 + R22*vM22;
        float G00 = vM00*sc0, G01 = vM01*sc1, G02 = vM02*sc2;
        float G10 = vM10*sc0, G11 = vM11*sc1, G12 = vM12*sc2;
        float G20 = vM20*sc0, G21 = vM21*sc1, G22 = vM22*sc2;
        float a_ = G21 - G12, b_ = G02 - G20, c_ = G10 - G01;
        float s1122 = G11 + G22, s0022 = G00 + G22, s0011 = G00 + G11;
        float pp01 = G10 + G01, pp02 = G20 + G02, pp12 = G21 + G12;
        float vq0 = 2.f*(qx*a_ + qy*b_ + qz*c_);
        float vq1 = 2.f*(-2.f*qx*s1122 + qy*pp01 + qz*pp02 + qw*a_);
        float vq2 = 2.f*(qx*pp01 - 2.f*qy*s0022 + qz*pp12 + qw*b_);
        float vq3 = 2.f*(qx*pp02 + qy*pp12 - 2.f*qz*s0011 + qw*c_);
        float dot = vq0*qw + vq1*qx + vq2*qy + vq3*qz;
        float o0 = (vq0 - dot*qw)*inv_norm;
        float o1 = (vq1 - dot*qx)*inv_norm;
        float o2 = (vq2 - dot*qy)*inv_norm;
        float o3 = (vq3 - dot*qz)*inv_norm;

        const int pwb = b*NPTS + n;
        out[O_PW + pwb*3 + 0] = vpw0;
        out[O_PW + pwb*3 + 1] = vpw1;
        out[O_PW + pwb*3 + 2] = vpw2;
        float4 qv = make_float4(o0, o1, o2, o3);
        *reinterpret_cast<float4*>(out + O_QU + pwb*4) = qv;
        out[O_SC + pwb*3 + 0] = vs0;
        out[O_SC + pwb*3 + 1] = vs1;
        out[O_SC + pwb*3 + 2] = vs2;
        out[O_CL + (b*3+0)*NPTS + n] = vcl0;
        out[O_CL + (b*3+1)*NPTS + n] = vcl1;
        out[O_CL + (b*3+2)*NPTS + n] = vcl2;
        out[O_OP + b*NPTS + n] = vopo;
    }
}

// ---------- kernel 3: finalize v_Rview ----------
__global__ void fin_kernel(const float* __restrict__ slots, float* __restrict__ out) {
    int t = threadIdx.x;
    if (t < 72) {
        float s = 0.f;
#pragma unroll
        for (int i = 0; i < NSLOT; i++) s += slots[i*72 + t];
        out[4000000 + t] = s;
    }
}

extern "C" void kernel_launch(void* const* d_in, const int* in_sizes, int n_in,
                              void* d_out, int out_size, void* d_ws, size_t ws_size,
                              hipStream_t stream) {
    (void)in_sizes; (void)n_in; (void)out_size; (void)ws_size;
    const float* means    = (const float*)d_in[0];
    const float* quats    = (const float*)d_in[1];
    const float* scales   = (const float*)d_in[2];
    const float* conics   = (const float*)d_in[3];
    const float* viewmats = (const float*)d_in[4];
    const float* Ks       = (const float*)d_in[5];
    const float* v_m2d    = (const float*)d_in[6];
    const float* v_dep    = (const float*)d_in[7];
    const float* v_con    = (const float*)d_in[8];
    const float* v_col    = (const float*)d_in[9];
    const float* v_op     = (const float*)d_in[10];
    const int* mask = (const int*)d_in[11];
    const int* pw   = (const int*)d_in[12];
    const int* ph   = (const int*)d_in[13];
    float* out = (float*)d_out;

    char* ws = (char*)d_ws;
    int*   prefix   = (int*)(ws + WS_PREFIX);
    int*   blocksum = (int*)(ws + WS_BLOCKSUM);
    float* slots    = (float*)(ws + WS_SLOTS);
    float* cam      = (float*)(ws + WS_CAM);

    scan1_kernel<<<dim3(NCHUNK + 1, 8), dim3(256), 0, stream>>>(
        mask, prefix, blocksum, slots, cam, viewmats, Ks, pw, ph);
    main_kernel<<<dim3(782, 2), dim3(256), 0, stream>>>(
        means, quats, scales, conics, v_m2d, v_dep, v_con, v_col, v_op,
        mask, prefix, blocksum, cam, slots, out);
    fin_kernel<<<dim3(1), dim3(128), 0, stream>>>(slots, out);
}

// Round 5
// 164.713 us; speedup vs baseline: 1.0772x; 1.0772x over previous
//
#include <hip/hip_runtime.h>

#define NPTS 200000
#define MWORDS 25000
#define NCHUNK 98          // ceil(25000/256) chunks of 256 words
#define NSLOT 64

// ---------- workspace layout (bytes) ----------
#define WS_PREFIX    0          // 8*25000*4 = 800000
#define WS_BLOCKSUM  800000     // 8*98*4    = 3136
#define WS_SLOTS     803136     // 64*72*4   = 18432
#define WS_CAM       821568     // 8*20*4    = 640

// ---------- DPP wave-64 reductions (sum lands in lane 63) ----------
__device__ __forceinline__ float wred_f(float x) {
    x += __int_as_float(__builtin_amdgcn_update_dpp(0, __float_as_int(x), 0x111, 0xf, 0xf, true)); // row_shr:1
    x += __int_as_float(__builtin_amdgcn_update_dpp(0, __float_as_int(x), 0x112, 0xf, 0xf, true)); // row_shr:2
    x += __int_as_float(__builtin_amdgcn_update_dpp(0, __float_as_int(x), 0x114, 0xf, 0xf, true)); // row_shr:4
    x += __int_as_float(__builtin_amdgcn_update_dpp(0, __float_as_int(x), 0x118, 0xf, 0xf, true)); // row_shr:8
    x += __int_as_float(__builtin_amdgcn_update_dpp(0, __float_as_int(x), 0x142, 0xf, 0xf, true)); // row_bcast:15
    x += __int_as_float(__builtin_amdgcn_update_dpp(0, __float_as_int(x), 0x143, 0xf, 0xf, true)); // row_bcast:31
    return x;
}
__device__ __forceinline__ int wred_i(int x) {
    x += __builtin_amdgcn_update_dpp(0, x, 0x111, 0xf, 0xf, true);
    x += __builtin_amdgcn_update_dpp(0, x, 0x112, 0xf, 0xf, true);
    x += __builtin_amdgcn_update_dpp(0, x, 0x114, 0xf, 0xf, true);
    x += __builtin_amdgcn_update_dpp(0, x, 0x118, 0xf, 0xf, true);
    x += __builtin_amdgcn_update_dpp(0, x, 0x142, 0xf, 0xf, true);
    x += __builtin_amdgcn_update_dpp(0, x, 0x143, 0xf, 0xf, true);
    return x;
}

// ---------- kernel P1: per-chunk local scan + blocksum + misc init ----------
__global__ __launch_bounds__(256) void scan1_kernel(const int* __restrict__ mask,
                                                    int* __restrict__ prefix,
                                                    int* __restrict__ blocksum,
                                                    float* __restrict__ slots,
                                                    float* __restrict__ cam,
                                                    const float* __restrict__ viewmats,
                                                    const float* __restrict__ Ks,
                                                    const int* __restrict__ pw,
                                                    const int* __restrict__ ph) {
    const int tid = threadIdx.x;
    if (blockIdx.x == NCHUNK) {               // misc block
        if (blockIdx.y != 0) return;
        for (int i = tid; i < NSLOT * 72; i += 256) slots[i] = 0.f;
        if (tid < 8) {
            const int bc = tid;
            float* cp = cam + bc * 20;
            const int vbase = bc * 16;
            for (int i = 0; i < 3; i++) {
                for (int j = 0; j < 3; j++) cp[i*3 + j] = viewmats[vbase + i*4 + j];
                cp[9 + i] = viewmats[vbase + i*4 + 3];
            }
            const int kbase = bc * 9;
            float fx = Ks[kbase + 0], fy = Ks[kbase + 4];
            float cx = Ks[kbase + 2], cy = Ks[kbase + 5];
            int wi = *pw, hi = *ph;
            float W = (wi >= 1 && wi <= (1 << 20)) ? (float)wi : __int_as_float(wi);
            float H = (hi >= 1 && hi <= (1 << 20)) ? (float)hi : __int_as_float(hi);
            float tanx = 0.5f * W / fx, tany = 0.5f * H / fy;
            cp[12] = fx; cp[13] = fy;
            cp[14] = (W - cx) / fx + 0.3f * tanx;
            cp[15] = cx / fx + 0.3f * tanx;
            cp[16] = (H - cy) / fy + 0.3f * tany;
            cp[17] = cy / fy + 0.3f * tany;
        }
        return;
    }
    const int bc    = blockIdx.y;
    const int chunk = blockIdx.x;
    const int lane  = tid & 63, wv = tid >> 6;
    const int w = chunk * 256 + tid;
    const int base = bc * MWORDS;

    int p = (w < MWORDS) ? __popc(mask[base + w]) : 0;
    int v = p;
#pragma unroll
    for (int off = 1; off < 64; off <<= 1) {
        int u = __shfl_up(v, off, 64);
        if (lane >= off) v += u;
    }
    __shared__ int wsum[4];
    if (lane == 63) wsum[wv] = v;
    __syncthreads();
    int wadd = 0;
#pragma unroll
    for (int i = 0; i < 4; i++) if (i < wv) wadd += wsum[i];
    if (w < MWORDS) prefix[base + w] = v - p + wadd;
    if (tid == 255) blocksum[bc * NCHUNK + chunk] = wadd + v;
}

// ---------- kernel 2: main backward (branchless camera bodies) ----------
__global__ __launch_bounds__(256) void main_kernel(
    const float* __restrict__ means,
    const float* __restrict__ quats,
    const float* __restrict__ scales,
    const float* __restrict__ conics,
    const float* __restrict__ v_m2d,
    const float* __restrict__ v_dep,
    const float* __restrict__ v_con,
    const float* __restrict__ v_col,
    const float* __restrict__ v_op,
    const int* __restrict__ mask,
    const int* __restrict__ prefix,
    const int* __restrict__ blocksum,
    const float* __restrict__ cam,
    float* __restrict__ slots,
    float* __restrict__ out)
{
    const int O_PW = 0, O_QU = 1200000, O_SC = 2800000, O_CL = 4000072, O_OP = 5200072;
    const int b = blockIdx.y;
    const int n = blockIdx.x * 256 + threadIdx.x;
    const bool act = (n < NPTS);
    const int nc = act ? n : (NPTS - 1);
    const int lane = threadIdx.x & 63, wv = threadIdx.x >> 6;
    const int slot = blockIdx.x & (NSLOT - 1);

    // ---- per-block chunk prefix (one camera per wave), DPP reduce ----
    const int chk = blockIdx.x >> 3;              // 256-word chunk id
    __shared__ int cpf_lds[4];
    {
        const int bcw = b * 4 + wv;
        int s0 = (lane < chk) ? blocksum[bcw * NCHUNK + lane] : 0;
        if (lane + 64 < chk) s0 += blocksum[bcw * NCHUNK + lane + 64];
        int tot = wred_i(s0);
        int t = __builtin_amdgcn_readlane(tot, 63);
        if (lane == 0) cpf_lds[wv] = t;
    }

    // hoisted mask/prefix loads for all 4 cameras
    const int w_ = nc >> 3, bit = nc & 7;
    int words[4], pref[4];
#pragma unroll
    for (int c = 0; c < 4; c++) {
        const int bc = b*4 + c;
        words[c] = mask[bc*MWORDS + w_];
        pref[c]  = prefix[bc*MWORDS + w_];
    }

    float mn0 = means[(b*3+0)*NPTS + nc];
    float mn1 = means[(b*3+1)*NPTS + nc];
    float mn2 = means[(b*3+2)*NPTS + nc];
    float q0 = quats[(b*4+0)*NPTS + nc];
    float q1 = quats[(b*4+1)*NPTS + nc];
    float q2 = quats[(b*4+2)*NPTS + nc];
    float q3 = quats[(b*4+3)*NPTS + nc];
    float sc0 = scales[(b*3+0)*NPTS + nc];
    float sc1 = scales[(b*3+1)*NPTS + nc];
    float sc2 = scales[(b*3+2)*NPTS + nc];
    float inv_norm = rsqrtf(q0*q0 + q1*q1 + q2*q2 + q3*q3);
    float qw = q0*inv_norm, qx = q1*inv_norm, qy = q2*inv_norm, qz = q3*inv_norm;
    float R00 = 1.f - 2.f*(qy*qy + qz*qz), R01 = 2.f*(qx*qy - qw*qz), R02 = 2.f*(qx*qz + qw*qy);
    float R10 = 2.f*(qx*qy + qw*qz), R11 = 1.f - 2.f*(qx*qx + qz*qz), R12 = 2.f*(qy*qz - qw*qx);
    float R20 = 2.f*(qx*qz - qw*qy), R21 = 2.f*(qy*qz + qw*qx), R22 = 1.f - 2.f*(qx*qx + qy*qy);
    float M00 = R00*sc0, M01 = R01*sc1, M02 = R02*sc2;
    float M10 = R10*sc0, M11 = R11*sc1, M12 = R12*sc2;
    float M20 = R20*sc0, M21 = R21*sc1, M22 = R22*sc2;
    float cv00 = M00*M00 + M01*M01 + M02*M02;
    float cv01 = M00*M10 + M01*M11 + M02*M12;
    float cv02 = M00*M20 + M01*M21 + M02*M22;
    float cv11 = M10*M10 + M11*M11 + M12*M12;
    float cv12 = M10*M20 + M11*M21 + M12*M22;
    float cv22 = M20*M20 + M21*M21 + M22*M22;

    float H00=0,H01=0,H02=0,H11=0,H12=0,H22=0;
    float vpw0=0,vpw1=0,vpw2=0;
    float vcl0=0,vcl1=0,vcl2=0, vopo=0;

    __shared__ float rbuf[4][36];
    __syncthreads();   // cpf_lds ready

#pragma unroll
    for (int c = 0; c < 4; c++) {
        const int bc = b*4 + c;
        const float* cp = cam + bc*20;
        const float gmul = (act && ((words[c] >> bit) & 1)) ? 1.f : 0.f;
        // rank: always in-range (r <= n) even when the bit is 0
        const int r = pref[c] + cpf_lds[c] + __popc(words[c] & ((1 << bit) - 1));
        const int base3 = bc*3*NPTS, base2 = bc*2*NPTS, base1 = bc*NPTS;
        // unconditional gathers (cacheline-shared with active neighbors), scaled by gmul
        float g_c0 = v_con[base3 + r] * gmul;
        float g_c1 = v_con[base3 + NPTS + r] * gmul;
        float g_c2 = v_con[base3 + 2*NPTS + r] * gmul;
        float g_m0 = v_m2d[base2 + r] * gmul;
        float g_m1 = v_m2d[base2 + NPTS + r] * gmul;
        float g_d  = v_dep[base1 + r] * gmul;
        float g_l0 = v_col[base3 + r] * gmul;
        float g_l1 = v_col[base3 + NPTS + r] * gmul;
        float g_l2 = v_col[base3 + 2*NPTS + r] * gmul;
        float g_o  = v_op[base1 + r] * gmul;
        float p00 = conics[base3 + nc];
        float p01 = conics[base3 + NPTS + nc];
        float p11 = conics[base3 + 2*NPTS + nc];
        const float V00=cp[0],V01=cp[1],V02=cp[2],V10=cp[3],V11=cp[4],V12=cp[5],V20=cp[6],V21=cp[7],V22=cp[8];
        const float t0=cp[9], t1=cp[10], t2=cp[11];
        const float fx=cp[12], fy=cp[13], lxp=cp[14], lxn=cp[15], lyp=cp[16], lyn=cp[17];
        // U = -P (v_ci) P   (symmetric); linear in g_c -> zero when gmul=0
        float a00 = g_c0, a01 = 0.5f*g_c1, a11 = g_c2;
        float q00 = a00*p00 + a01*p01, q01 = a00*p01 + a01*p11;
        float q10 = a01*p00 + a11*p01, q11 = a01*p01 + a11*p11;
        float u00 = -(p00*q00 + p01*q10), u01 = -(p00*q01 + p01*q11);
        float u10 = -(p01*q00 + p11*q10), u11 = -(p01*q01 + p11*q11);
        // mean_c
        float mx = V00*mn0 + V01*mn1 + V02*mn2 + t0;
        float my = V10*mn0 + V11*mn1 + V12*mn2 + t1;
        float tz = V20*mn0 + V21*mn1 + V22*mn2 + t2;
        float rz = 1.0f / tz;
        float rz2 = rz*rz, rz3 = rz2*rz;
        // T = Rv @ covars ; covar_c = T @ Rv^T (sym)
        float T00 = V00*cv00 + V01*cv01 + V02*cv02;
        float T01 = V00*cv01 + V01*cv11 + V02*cv12;
        float T02 = V00*cv02 + V01*cv12 + V02*cv22;
        float T10 = V10*cv00 + V11*cv01 + V12*cv02;
        float T11 = V10*cv01 + V11*cv11 + V12*cv12;
        float T12 = V10*cv02 + V11*cv12 + V12*cv22;
        float T20 = V20*cv00 + V21*cv01 + V22*cv02;
        float T21 = V20*cv01 + V21*cv11 + V22*cv12;
        float T22 = V20*cv02 + V21*cv12 + V22*cv22;
        float cc00 = T00*V00 + T01*V01 + T02*V02;
        float cc01 = T00*V10 + T01*V11 + T02*V12;
        float cc02 = T00*V20 + T01*V21 + T02*V22;
        float cc11 = T10*V10 + T11*V11 + T12*V12;
        float cc12 = T10*V20 + T11*V21 + T12*V22;
        float cc22 = T20*V20 + T21*V21 + T22*V22;
        // J terms
        float mxz = mx*rz, myz = my*rz;
        float xf = (mxz <= lxp && mxz >= -lxn) ? 1.f : 0.f;
        float yf = (myz <= lyp && myz >= -lyn) ? 1.f : 0.f;
        float tx = tz * fminf(fmaxf(mxz, -lxn), lxp);
        float ty = tz * fminf(fmaxf(myz, -lyn), lyp);
        float j00 = fx*rz, j02 = -fx*tx*rz2;
        float j11 = fy*rz, j12 = -fy*ty*rz2;
        // D = J^T U J ; S = D + D^T
        float W0a = u00*j00, W0b = u01*j11, W0c = u00*j02 + u01*j12;
        float W1a = u10*j00, W1b = u11*j11, W1c = u10*j02 + u11*j12;
        float d00 = j00*W0a, d01 = j00*W0b, d02 = j00*W0c;
        float d10 = j11*W1a, d11 = j11*W1b, d12 = j11*W1c;
        float d20 = j02*W0a + j12*W1a, d21 = j02*W0b + j12*W1b, d22 = j02*W0c + j12*W1c;
        float s00 = d00+d00, s01 = d01+d10, s02 = d02+d20;
        float s11 = d11+d11, s12 = d12+d21, s22 = d22+d22;
        // v_J = (2U) J covar_c
        float e00 = u00+u00, e01 = u01+u10, e11 = u11+u11;
        float X00 = e00*j00, X01 = e01*j11, X02 = e00*j02 + e01*j12;
        float X10 = e01*j00, X11 = e11*j11, X12 = e01*j02 + e11*j12;
        float vJ00 = X00*cc00 + X01*cc01 + X02*cc02;
        float vJ02 = X00*cc02 + X01*cc12 + X02*cc22;
        float vJ11 = X10*cc01 + X11*cc11 + X12*cc12;
        float vJ12 = X10*cc02 + X11*cc12 + X12*cc22;
        // v_mean_c  (linear in g_m/g_d/vJ -> zero when gmul=0)
        float m0 = fx*rz*g_m0;
        float m1 = fy*rz*g_m1;
        float m2 = -(fx*mx*g_m0 + fy*my*g_m1)*rz2;
        m0 -= fx*rz2*vJ02*xf;
        m2 -= fx*rz3*vJ02*tx*(1.f - xf);
        m1 -= fy*rz2*vJ12*yf;
        m2 -= fy*rz3*vJ12*ty*(1.f - yf);
        m2 += -fx*rz2*vJ00 - fy*rz2*vJ11 + 2.f*fx*tx*rz3*vJ02 + 2.f*fy*ty*rz3*vJ12;
        m2 += g_d;
        // v_pW += Rv^T v_mean_c
        vpw0 += V00*m0 + V10*m1 + V20*m2;
        vpw1 += V01*m0 + V11*m1 + V21*m2;
        vpw2 += V02*m0 + V12*m1 + V22*m2;
        // v_Rview contribution = m ⊗ mean + S @ T  -> DPP wave reduce now
        float rv0 = m0*mn0 + (s00*T00 + s01*T10 + s02*T20);
        float rv1 = m0*mn1 + (s00*T01 + s01*T11 + s02*T21);
        float rv2 = m0*mn2 + (s00*T02 + s01*T12 + s02*T22);
        float rv3 = m1*mn0 + (s01*T00 + s11*T10 + s12*T20);
        float rv4 = m1*mn1 + (s01*T01 + s11*T11 + s12*T21);
        float rv5 = m1*mn2 + (s01*T02 + s11*T12 + s12*T22);
        float rv6 = m2*mn0 + (s02*T00 + s12*T10 + s22*T20);
        float rv7 = m2*mn1 + (s02*T01 + s12*T11 + s22*T21);
        float rv8 = m2*mn2 + (s02*T02 + s12*T12 + s22*T22);
        rv0 = wred_f(rv0); rv1 = wred_f(rv1); rv2 = wred_f(rv2);
        rv3 = wred_f(rv3); rv4 = wred_f(rv4); rv5 = wred_f(rv5);
        rv6 = wred_f(rv6); rv7 = wred_f(rv7); rv8 = wred_f(rv8);
        if (lane == 63) {
            rbuf[wv][c*9+0] = rv0; rbuf[wv][c*9+1] = rv1; rbuf[wv][c*9+2] = rv2;
            rbuf[wv][c*9+3] = rv3; rbuf[wv][c*9+4] = rv4; rbuf[wv][c*9+5] = rv5;
            rbuf[wv][c*9+6] = rv6; rbuf[wv][c*9+7] = rv7; rbuf[wv][c*9+8] = rv8;
        }
        // H += Rv^T S Rv
        float P00 = s00*V00 + s01*V10 + s02*V20;
        float P01 = s00*V01 + s01*V11 + s02*V21;
        float P02 = s00*V02 + s01*V12 + s02*V22;
        float P10 = s01*V00 + s11*V10 + s12*V20;
        float P11 = s01*V01 + s11*V11 + s12*V21;
        float P12 = s01*V02 + s11*V12 + s12*V22;
        float P20 = s02*V00 + s12*V10 + s22*V20;
        float P21 = s02*V01 + s12*V11 + s22*V21;
        float P22 = s02*V02 + s12*V12 + s22*V22;
        H00 += V00*P00 + V10*P10 + V20*P20;
        H01 += V00*P01 + V10*P11 + V20*P21;
        H02 += V00*P02 + V10*P12 + V20*P22;
        H11 += V01*P01 + V11*P11 + V21*P21;
        H12 += V01*P02 + V11*P12 + V21*P22;
        H22 += V02*P02 + V12*P12 + V22*P22;
        vcl0 += g_l0; vcl1 += g_l1; vcl2 += g_l2; vopo += g_o;
    }

    __syncthreads();
    if (threadIdx.x < 36) {
        float s = rbuf[0][threadIdx.x] + rbuf[1][threadIdx.x] +
                  rbuf[2][threadIdx.x] + rbuf[3][threadIdx.x];
        atomicAdd(&slots[slot*72 + b*36 + threadIdx.x], s);
    }

    if (act) {
        // v_M = H @ Mm
        float vM00 = H00*M00 + H01*M10 + H02*M20;
        float vM01 = H00*M01 + H01*M11 + H02*M21;
        float vM02 = H00*M02 + H01*M12 + H02*M22;
        float vM10 = H01*M00 + H11*M10 + H12*M20;
        float vM11 = H01*M01 + H11*M11 + H12*M21;
        float vM12 = H01*M02 + H11*M12 + H12*M22;
        float vM20 = H02*M00 + H12*M10 + H22*M20;
        float vM21 = H02*M01 + H12*M11 + H22*M21;
        float vM22 = H02*M02 + H12*M12 + H22*M22;
        float vs0 = R00*vM00 + R10*vM10 + R20*vM20;
        float vs1 = R01*vM01 + R11*vM11 + R21*vM21;
        float vs2 = R02*vM02 + R12*vM12 + R22*vM22;
        float G00 = vM00*sc0, G01 = vM01*sc1, G02 = vM02*sc2;
        float G10 = vM10*sc0, G11 = vM11*sc1, G12 = vM12*sc2;
        float G20 = vM20*sc0, G21 = vM21*sc1, G22 = vM22*sc2;
        float a_ = G21 - G12, b_ = G02 - G20, c_ = G10 - G01;
        float s1122 = G11 + G22, s0022 = G00 + G22, s0011 = G00 + G11;
        float pp01 = G10 + G01, pp02 = G20 + G02, pp12 = G21 + G12;
        float vq0 = 2.f*(qx*a_ + qy*b_ + qz*c_);
        float vq1 = 2.f*(-2.f*qx*s1122 + qy*pp01 + qz*pp02 + qw*a_);
        float vq2 = 2.f*(qx*pp01 - 2.f*qy*s0022 + qz*pp12 + qw*b_);
        float vq3 = 2.f*(qx*pp02 + qy*pp12 - 2.f*qz*s0011 + qw*c_);
        float dot = vq0*qw + vq1*qx + vq2*qy + vq3*qz;
        float o0 = (vq0 - dot*qw)*inv_norm;
        float o1 = (vq1 - dot*qx)*inv_norm;
        float o2 = (vq2 - dot*qy)*inv_norm;
        float o3 = (vq3 - dot*qz)*inv_norm;

        const int pwb = b*NPTS + n;
        out[O_PW + pwb*3 + 0] = vpw0;
        out[O_PW + pwb*3 + 1] = vpw1;
        out[O_PW + pwb*3 + 2] = vpw2;
        float4 qv = make_float4(o0, o1, o2, o3);
        *reinterpret_cast<float4*>(out + O_QU + pwb*4) = qv;
        out[O_SC + pwb*3 + 0] = vs0;
        out[O_SC + pwb*3 + 1] = vs1;
        out[O_SC + pwb*3 + 2] = vs2;
        out[O_CL + (b*3+0)*NPTS + n] = vcl0;
        out[O_CL + (b*3+1)*NPTS + n] = vcl1;
        out[O_CL + (b*3+2)*NPTS + n] = vcl2;
        out[O_OP + b*NPTS + n] = vopo;
    }
}

// ---------- kernel 3: finalize v_Rview ----------
__global__ void fin_kernel(const float* __restrict__ slots, float* __restrict__ out) {
    int t = threadIdx.x;
    if (t < 72) {
        float s = 0.f;
#pragma unroll
        for (int i = 0; i < NSLOT; i++) s += slots[i*72 + t];
        out[4000000 + t] = s;
    }
}

extern "C" void kernel_launch(void* const* d_in, const int* in_sizes, int n_in,
                              void* d_out, int out_size, void* d_ws, size_t ws_size,
                              hipStream_t stream) {
    (void)in_sizes; (void)n_in; (void)out_size; (void)ws_size;
    const float* means    = (const float*)d_in[0];
    const float* quats    = (const float*)d_in[1];
    const float* scales   = (const float*)d_in[2];
    const float* conics   = (const float*)d_in[3];
    const float* viewmats = (const float*)d_in[4];
    const float* Ks       = (const float*)d_in[5];
    const float* v_m2d    = (const float*)d_in[6];
    const float* v_dep    = (const float*)d_in[7];
    const float* v_con    = (const float*)d_in[8];
    const float* v_col    = (const float*)d_in[9];
    const float* v_op     = (const float*)d_in[10];
    const int* mask = (const int*)d_in[11];
    const int* pw   = (const int*)d_in[12];
    const int* ph   = (const int*)d_in[13];
    float* out = (float*)d_out;

    char* ws = (char*)d_ws;
    int*   prefix   = (int*)(ws + WS_PREFIX);
    int*   blocksum = (int*)(ws + WS_BLOCKSUM);
    float* slots    = (float*)(ws + WS_SLOTS);
    float* cam      = (float*)(ws + WS_CAM);

    scan1_kernel<<<dim3(NCHUNK + 1, 8), dim3(256), 0, stream>>>(
        mask, prefix, blocksum, slots, cam, viewmats, Ks, pw, ph);
    main_kernel<<<dim3(782, 2), dim3(256), 0, stream>>>(
        means, quats, scales, conics, v_m2d, v_dep, v_con, v_col, v_op,
        mask, prefix, blocksum, cam, slots, out);
    fin_kernel<<<dim3(1), dim3(128), 0, stream>>>(slots, out);
}